// Round 4
// baseline (22.010 us; speedup 1.0000x reference)
//
#include <hip/hip_runtime.h>
#include <cfloat>

// Problem constants (fixed by the reference)
#define N_PTS 65536
#define M_PTS 1024
#define WAVES 16
#define BLOCK (WAVES * 64)          // 1024 threads
#define QPB   256                   // queries per block (4 per lane)
#define CHUNK (M_PTS / WAVES)       // 64 maze points per wave

typedef float f32x2 __attribute__((ext_vector_type(2)));
typedef float f32x4 __attribute__((ext_vector_type(4)));

// Each lane owns 4 query points (amortizes every maze-point LDS read over 4
// queries -> LDS traffic /4 vs R2). Each of the 16 waves scans a contiguous
// 64-point maze chunk for the block's 256 queries; candidates merged in LDS
// with ascending-index tie-break. All f32 math is exact, contraction OFF, in
// the reference op order (diff, square, (dx2+dy2)+dz2) -> bit-identical
// distances -> exact argmin agreement.
__global__ __launch_bounds__(BLOCK) void linearize_kernel(
    const float* __restrict__ ed,   // [N,3] euclidean_data
    const float* __restrict__ mp,   // [M,3] maze_points
    const float* __restrict__ ts,   // [M]   ts_proj
    float* __restrict__ out)        // [N*3] projected_pos ++ [N] linear_pos
{
#pragma clang fp contract(off)
    __shared__ float soa[3][M_PTS];     // 12 KB maze SoA
    __shared__ float s_d[WAVES][QPB];   // 16 KB candidate distances
    __shared__ int   s_i[WAVES][QPB];   // 16 KB candidate indices

    const int tid = threadIdx.x;

    // Stage maze AoS->SoA (3072 coalesced dwords, 3 per thread).
    #pragma unroll
    for (int j = tid; j < 3 * M_PTS; j += BLOCK) {
        soa[j % 3][j / 3] = mp[j];
    }

    const int lane = tid & 63;
    const int w = tid >> 6;
    const int qbase = blockIdx.x * QPB + lane * 4;   // first of this lane's 4 queries

    // 48B contiguous per lane -> 3 x dwordx4, fully coalesced across the wave.
    const f32x4 e0 = *(const f32x4*)&ed[qbase * 3 + 0];  // q0.xyz q1.x
    const f32x4 e1 = *(const f32x4*)&ed[qbase * 3 + 4];  // q1.yz  q2.xy
    const f32x4 e2 = *(const f32x4*)&ed[qbase * 3 + 8];  // q2.z   q3.xyz

    // Query pairs A=(q0,q1), B=(q2,q3) as packed f32x2 per coordinate.
    const f32x2 ax = {e0.x, e0.w};
    const f32x2 ay = {e0.y, e1.x};
    const f32x2 az = {e0.z, e1.y};
    const f32x2 bx = {e1.z, e2.y};
    const f32x2 by = {e1.w, e2.z};
    const f32x2 bz = {e2.x, e2.w};

    __syncthreads();

    float d0 = FLT_MAX, d1 = FLT_MAX, d2 = FLT_MAX, d3 = FLT_MAX;
    int   b0 = 0, b1 = 0, b2 = 0, b3 = 0;
    const int m0 = w * CHUNK;

    #pragma unroll 2
    for (int k = 0; k < CHUNK; k += 4) {
        const int m = m0 + k;
        // Wave-uniform broadcast reads: 4 consecutive maze points per dim.
        const f32x4 px = *(const f32x4*)&soa[0][m];
        const f32x4 py = *(const f32x4*)&soa[1][m];
        const f32x4 pz = *(const f32x4*)&soa[2][m];

        #define STEP(T) do {                                              \
            const f32x2 msx = {px[T], px[T]};                             \
            const f32x2 msy = {py[T], py[T]};                             \
            const f32x2 msz = {pz[T], pz[T]};                             \
            const f32x2 dxa = ax - msx, dya = ay - msy, dza = az - msz;   \
            const f32x2 da  = (dxa*dxa + dya*dya) + dza*dza;              \
            const f32x2 dxb = bx - msx, dyb = by - msy, dzb = bz - msz;   \
            const f32x2 db  = (dxb*dxb + dyb*dyb) + dzb*dzb;              \
            if (da.x < d0) { d0 = da.x; b0 = m + T; }                     \
            if (da.y < d1) { d1 = da.y; b1 = m + T; }                     \
            if (db.x < d2) { d2 = db.x; b2 = m + T; }                     \
            if (db.y < d3) { d3 = db.y; b3 = m + T; }                     \
        } while (0)
        STEP(0); STEP(1); STEP(2); STEP(3);
        #undef STEP
    }

    // Publish per-wave candidates.
    s_d[w][lane * 4 + 0] = d0;  s_i[w][lane * 4 + 0] = b0;
    s_d[w][lane * 4 + 1] = d1;  s_i[w][lane * 4 + 1] = b1;
    s_d[w][lane * 4 + 2] = d2;  s_i[w][lane * 4 + 2] = b2;
    s_d[w][lane * 4 + 3] = d3;  s_i[w][lane * 4 + 3] = b3;
    __syncthreads();

    // Merge the 16 per-wave candidates per query. Chunks are ascending index
    // ranges scanned with strict '<' -> global first-argmin (jnp.argmin).
    if (tid < QPB) {
        float dmin = s_d[0][tid];
        int   best = s_i[0][tid];
        #pragma unroll
        for (int j = 1; j < WAVES; ++j) {
            const float od = s_d[j][tid];
            const int   ob = s_i[j][tid];
            if (od < dmin || (od == dmin && ob < best)) { dmin = od; best = ob; }
        }
        const int i = blockIdx.x * QPB + tid;
        // Gathers are bit-exact copies of maze data (LDS/L1-resident).
        out[i * 3 + 0]     = soa[0][best];
        out[i * 3 + 1]     = soa[1][best];
        out[i * 3 + 2]     = soa[2][best];
        out[N_PTS * 3 + i] = ts[best];
    }
}

extern "C" void kernel_launch(void* const* d_in, const int* in_sizes, int n_in,
                              void* d_out, int out_size, void* d_ws, size_t ws_size,
                              hipStream_t stream) {
    const float* ed = (const float*)d_in[0];
    const float* mp = (const float*)d_in[1];
    const float* ts = (const float*)d_in[2];
    float* out = (float*)d_out;

    const int grid = N_PTS / QPB;   // 256 blocks x 1024 threads = 4096 waves
    linearize_kernel<<<grid, BLOCK, 0, stream>>>(ed, mp, ts, out);
}